// Round 1
// baseline (440.560 us; speedup 1.0000x reference)
//
#include <hip/hip_runtime.h>
#include <hip/hip_bf16.h>

#define E_EDGES 500000
#define NN 50000

typedef unsigned short u16;
typedef __attribute__((ext_vector_type(8))) short s16x8;
typedef __attribute__((ext_vector_type(4))) float f32x4;

__device__ __forceinline__ short f2bf(float f) {
    unsigned u = __builtin_bit_cast(unsigned, f);
    u += 0x7fffu + ((u >> 16) & 1u);
    return (short)(u >> 16);
}

__device__ __forceinline__ float lrelu(float x) { return x > 0.0f ? x : 0.01f * x; }

// ---- weight prep: WT[g][n][k] = bf16(W_g[k][n]), g in {src, tgt, edge} ----
__global__ void kprep(const float* __restrict__ Wsrc, const float* __restrict__ Wtgt,
                      const float* __restrict__ Wedge, u16* __restrict__ WT) {
    int i = blockIdx.x * 256 + threadIdx.x;
    if (i >= 3 * 16384) return;
    int g = i >> 14, nk = i & 16383, n = nk >> 7, k = nk & 127;
    const float* W = (g == 0) ? Wsrc : (g == 1) ? Wtgt : Wedge;
    WT[i] = (u16)f2bf(W[k * 128 + n]);
}

// ---- shared staging helpers ----
__device__ __forceinline__ void stage_A(const float* __restrict__ X, int blockRow,
                                        u16 (*ldsA)[136], int tid) {
#pragma unroll
    for (int it = 0; it < 8; ++it) {
        int chunk = it * 256 + tid;          // 2048 chunks of 8 elems = 128x128
        int row = chunk >> 4, kc = (chunk & 15) << 3;
        int ge = blockRow + row;
        float4 v0 = {0.f, 0.f, 0.f, 0.f}, v1 = {0.f, 0.f, 0.f, 0.f};
        if (ge < E_EDGES) {
            const float* p = X + (size_t)ge * 128 + kc;
            v0 = *(const float4*)p;
            v1 = *(const float4*)(p + 4);
        }
        s16x8 w;
        w[0] = f2bf(v0.x); w[1] = f2bf(v0.y); w[2] = f2bf(v0.z); w[3] = f2bf(v0.w);
        w[4] = f2bf(v1.x); w[5] = f2bf(v1.y); w[6] = f2bf(v1.z); w[7] = f2bf(v1.w);
        *(s16x8*)&ldsA[row][kc] = w;
    }
}

__device__ __forceinline__ void stage_B(const u16* __restrict__ WTg,
                                        u16 (*ldsB)[136], int tid) {
#pragma unroll
    for (int it = 0; it < 8; ++it) {
        int chunk = it * 256 + tid;
        int n = chunk >> 4, kc = (chunk & 15) << 3;
        s16x8 w = *(const s16x8*)(WTg + n * 128 + kc);
        *(s16x8*)&ldsB[n][kc] = w;
    }
}

__device__ __forceinline__ void mfma_tile(const u16 (*ldsA)[136], const u16 (*ldsB)[136],
                                          f32x4 (&acc)[2][8], int wv, int l15, int lg) {
#pragma unroll
    for (int kk = 0; kk < 4; ++kk) {
        int k0 = kk * 32 + lg * 8;
        s16x8 a0 = *(const s16x8*)&ldsA[wv * 32 + l15][k0];
        s16x8 a1 = *(const s16x8*)&ldsA[wv * 32 + 16 + l15][k0];
#pragma unroll
        for (int n = 0; n < 8; ++n) {
            s16x8 b = *(const s16x8*)&ldsB[n * 16 + l15][k0];
            acc[0][n] = __builtin_amdgcn_mfma_f32_16x16x32_bf16(a0, b, acc[0][n], 0, 0, 0);
            acc[1][n] = __builtin_amdgcn_mfma_f32_16x16x32_bf16(a1, b, acc[1][n], 0, 0, 0);
        }
    }
}

// ---- K1: q = s@Ws + r@Wt + e@We ; z = sum_c leaky(q)*attn ; ez=exp(z); denom atomic ----
__global__ __launch_bounds__(256, 2) void k1(
    const float* __restrict__ recv, const float* __restrict__ send,
    const float* __restrict__ eattr, const int* __restrict__ sidx,
    const u16* __restrict__ WT, const float* __restrict__ attn,
    float* __restrict__ ez, float* __restrict__ denom)
{
    __shared__ u16 ldsA[128][136];
    __shared__ u16 ldsB[128][136];
    int tid = threadIdx.x;
    int lane = tid & 63, wv = tid >> 6;
    int l15 = lane & 15, lg = lane >> 4;
    int blockRow = blockIdx.x * 128;

    f32x4 acc[2][8];
#pragma unroll
    for (int m = 0; m < 2; ++m)
#pragma unroll
        for (int n = 0; n < 8; ++n) acc[m][n] = (f32x4){0.f, 0.f, 0.f, 0.f};

#pragma unroll
    for (int g = 0; g < 3; ++g) {
        const float* X = (g == 0) ? send : (g == 1) ? recv : eattr;
        if (g) __syncthreads();
        stage_A(X, blockRow, ldsA, tid);
        stage_B(WT + g * 16384, ldsB, tid);
        __syncthreads();
        mfma_tile(ldsA, ldsB, acc, wv, l15, lg);
    }

    // attn coefficient for this lane's column in each n-fragment
    float av[8];
#pragma unroll
    for (int n = 0; n < 8; ++n) av[n] = attn[n * 16 + l15];

#pragma unroll
    for (int m = 0; m < 2; ++m) {
#pragma unroll
        for (int h = 0; h < 4; ++h) {
            float part[4];
#pragma unroll
            for (int j = 0; j < 4; ++j)
                part[j] = lrelu(acc[m][2 * h][j]) * av[2 * h] +
                          lrelu(acc[m][2 * h + 1][j]) * av[2 * h + 1];
            // butterfly over the 16 lanes sharing a row group (sums columns)
#pragma unroll
            for (int off = 1; off < 16; off <<= 1) {
#pragma unroll
                for (int j = 0; j < 4; ++j) part[j] += __shfl_xor(part[j], off, 64);
            }
            if (l15 == h) {
#pragma unroll
                for (int j = 0; j < 4; ++j) {
                    int r = blockRow + wv * 32 + m * 16 + lg * 4 + j;
                    if (r < E_EDGES) {
                        float ezv = __expf(part[j]);
                        ez[(size_t)r * 4 + h] = ezv;
                        atomicAdd(&denom[(size_t)sidx[r] * 4 + h], ezv);
                    }
                }
            }
        }
    }
}

// ---- K_a: a = ez / denom[sender] (in place) ----
__global__ void ka(float* __restrict__ eza, const float* __restrict__ denom,
                   const int* __restrict__ sidx) {
    int e = blockIdx.x * 256 + threadIdx.x;
    if (e >= E_EDGES) return;
    float4 z = *(float4*)(eza + (size_t)e * 4);
    int s = sidx[e];
    float4 d = *(const float4*)(denom + (size_t)s * 4);
    z.x /= d.x; z.y /= d.y; z.z /= d.z; z.w /= d.w;
    *(float4*)(eza + (size_t)e * 4) = z;
}

// ---- K2: t = r@Wt ; m_mean = 0.25*sum_h t*a ; out1 store; out0 atomic segment-sum ----
__global__ __launch_bounds__(256, 2) void k2(
    const float* __restrict__ recv, const int* __restrict__ ridx,
    const u16* __restrict__ WTt, const float* __restrict__ a,
    float* __restrict__ out0, float* __restrict__ out1)
{
    __shared__ u16 ldsA[128][136];
    __shared__ u16 ldsB[128][136];
    int tid = threadIdx.x;
    int lane = tid & 63, wv = tid >> 6;
    int l15 = lane & 15, lg = lane >> 4;
    int blockRow = blockIdx.x * 128;

    f32x4 acc[2][8];
#pragma unroll
    for (int m = 0; m < 2; ++m)
#pragma unroll
        for (int n = 0; n < 8; ++n) acc[m][n] = (f32x4){0.f, 0.f, 0.f, 0.f};

    stage_A(recv, blockRow, ldsA, tid);
    stage_B(WTt, ldsB, tid);
    __syncthreads();
    mfma_tile(ldsA, ldsB, acc, wv, l15, lg);

#pragma unroll
    for (int m = 0; m < 2; ++m) {
#pragma unroll
        for (int j = 0; j < 4; ++j) {
            int r = blockRow + wv * 32 + m * 16 + lg * 4 + j;
            if (r < E_EDGES) {
                float4 av = *(const float4*)(a + (size_t)r * 4);
                // head h lives in n-frags {2h (c<16), 2h+1 (c>=16)}
                float lo = 0.25f * (acc[m][0][j] * av.x + acc[m][2][j] * av.y +
                                    acc[m][4][j] * av.z + acc[m][6][j] * av.w);
                float hi = 0.25f * (acc[m][1][j] * av.x + acc[m][3][j] * av.y +
                                    acc[m][5][j] * av.z + acc[m][7][j] * av.w);
                out1[(size_t)r * 32 + l15] = lo;
                out1[(size_t)r * 32 + 16 + l15] = hi;
                int rv = ridx[r];
                atomicAdd(&out0[(size_t)rv * 32 + l15], lo);
                atomicAdd(&out0[(size_t)rv * 32 + 16 + l15], hi);
            }
        }
    }
}

extern "C" void kernel_launch(void* const* d_in, const int* in_sizes, int n_in,
                              void* d_out, int out_size, void* d_ws, size_t ws_size,
                              hipStream_t stream) {
    const float* recv  = (const float*)d_in[0];
    const float* send  = (const float*)d_in[1];
    const float* eattr = (const float*)d_in[2];
    const int*   sidx  = (const int*)d_in[3];
    const int*   ridx  = (const int*)d_in[4];
    const float* Wsrc  = (const float*)d_in[5];
    const float* Wtgt  = (const float*)d_in[6];
    const float* Wedge = (const float*)d_in[7];
    const float* attn  = (const float*)d_in[8];

    char* ws = (char*)d_ws;
    u16*   WT    = (u16*)ws;                         // 3*128*128*2 = 98304 B
    float* ez    = (float*)(ws + 131072);            // E*4*4 = 8,000,000 B
    float* denom = (float*)(ws + 131072 + 8000000);  // N*4*4 = 800,000 B

    float* out0 = (float*)d_out;                     // [N,32]
    float* out1 = out0 + (size_t)NN * 32;            // [E,32]

    hipMemsetAsync(denom, 0, (size_t)NN * 4 * sizeof(float), stream);
    hipMemsetAsync(out0, 0, (size_t)NN * 32 * sizeof(float), stream);

    kprep<<<192, 256, 0, stream>>>(Wsrc, Wtgt, Wedge, WT);

    int nb = (E_EDGES + 127) / 128;  // 3907
    k1<<<nb, 256, 0, stream>>>(recv, send, eattr, sidx, WT, attn, ez, denom);
    ka<<<(E_EDGES + 255) / 256, 256, 0, stream>>>(ez, denom, sidx);
    k2<<<nb, 256, 0, stream>>>(recv, ridx, WT + 16384, ez, out0, out1);
}